// Round 1
// baseline (121.686 us; speedup 1.0000x reference)
//
#include <hip/hip_runtime.h>
#include <float.h>

#define BATCH   8
#define NPTS    4096
#define TILE    64        // x points per block (one per lane)
#define THREADS 256
#define YSTAGE  2048      // y points staged per LDS pass
#define BLOCKS_PER_DIR (BATCH * (NPTS / TILE))   // 512
#define TOTAL_BLOCKS   (2 * BLOCKS_PER_DIR)      // 1024

// Each block: one direction, one batch, 64 x-points (lane-owned).
// Wave w (quad) scans y-quadrant w. LDS holds y pre-transformed to
// (-2*y0, -2*y1, -2*y2, |y|^2) so the inner loop is 1 ds_read_b128 + 4 VALU + 1 min.
__global__ __launch_bounds__(THREADS) void chamfer_min_kernel(
    const float* __restrict__ A, const float* __restrict__ Bp,
    float* __restrict__ partials)
{
    __shared__ float4 ys[YSTAGE];        // 32 KB
    __shared__ float  smin[THREADS];

    const int bid  = blockIdx.x;
    const int dir  = bid >> 9;           // 0: x=A,y=B  1: x=B,y=A
    const int sub  = bid & 511;
    const int b    = sub >> 6;
    const int tile = sub & 63;
    const int tid  = threadIdx.x;
    const int lane = tid & 63;
    const int quad = tid >> 6;           // == wave id within block

    const float* xbase = (dir == 0 ? A : Bp) + (size_t)b * NPTS * 3;
    const float* ybase = (dir == 0 ? Bp : A) + (size_t)b * NPTS * 3;

    const int xi = tile * TILE + lane;
    const float x0 = xbase[xi * 3 + 0];
    const float x1 = xbase[xi * 3 + 1];
    const float x2 = xbase[xi * 3 + 2];
    const float xs = x0 * x0 + x1 * x1 + x2 * x2;

    float mn = FLT_MAX;
    #pragma unroll
    for (int s = 0; s < NPTS / YSTAGE; ++s) {
        __syncthreads();
        // stage YSTAGE y-points, pre-scaled
        for (int p = tid; p < YSTAGE; p += THREADS) {
            const float* g = ybase + (size_t)(s * YSTAGE + p) * 3;
            const float y0 = g[0], y1 = g[1], y2 = g[2];
            ys[p] = make_float4(-2.f * y0, -2.f * y1, -2.f * y2,
                                y0 * y0 + y1 * y1 + y2 * y2);
        }
        __syncthreads();
        const int base = quad * (YSTAGE / 4);
        #pragma unroll 8
        for (int m = 0; m < YSTAGE / 4; ++m) {
            const float4 ly = ys[base + m];   // wave-uniform address -> broadcast
            const float d2 = fmaf(x0, ly.x,
                             fmaf(x1, ly.y,
                             fmaf(x2, ly.z, xs + ly.w)));
            mn = fminf(mn, d2);
        }
    }

    smin[tid] = mn;
    __syncthreads();
    if (tid < 64) {
        float m4 = fminf(fminf(smin[tid],       smin[tid + 64]),
                         fminf(smin[tid + 128], smin[tid + 192]));
        m4 = fmaxf(m4, 0.0f);                 // clamp after min (monotone)
        // wave-64 sum of the 64 x-point mins
        #pragma unroll
        for (int off = 32; off > 0; off >>= 1)
            m4 += __shfl_down(m4, off, 64);
        if (tid == 0) partials[bid] = m4;
    }
}

// Deterministic fixed-order reduction of the 1024 block partials.
__global__ __launch_bounds__(256) void chamfer_final_kernel(
    const float* __restrict__ partials, float* __restrict__ out)
{
    __shared__ float r0[256], r1[256];
    const int tid = threadIdx.x;
    r0[tid] = partials[tid]       + partials[tid + 256];   // dir 0 (512 partials)
    r1[tid] = partials[512 + tid] + partials[768 + tid];   // dir 1
    __syncthreads();
    #pragma unroll
    for (int s = 128; s > 0; s >>= 1) {
        if (tid < s) { r0[tid] += r0[tid + s]; r1[tid] += r1[tid + s]; }
        __syncthreads();
    }
    if (tid == 0)
        out[0] = r0[0] * (1.0f / (BATCH * NPTS)) + r1[0] * (1.0f / (BATCH * NPTS));
}

extern "C" void kernel_launch(void* const* d_in, const int* in_sizes, int n_in,
                              void* d_out, int out_size, void* d_ws, size_t ws_size,
                              hipStream_t stream) {
    const float* A = (const float*)d_in[0];   // coor_recon [8,4096,3]
    const float* B = (const float*)d_in[1];   // pc_gd      [8,4096,3]
    float* partials = (float*)d_ws;           // 1024 floats, fully rewritten each call
    float* out = (float*)d_out;

    chamfer_min_kernel<<<TOTAL_BLOCKS, THREADS, 0, stream>>>(A, B, partials);
    chamfer_final_kernel<<<1, 256, 0, stream>>>(partials, out);
}

// Round 2
// 28.937 us; speedup vs baseline: 4.2052x; 4.2052x over previous
//
#include <hip/hip_runtime.h>
#include <float.h>

#define BATCH   8
#define NPTS    4096
#define THREADS 512
#define NWAVE   (THREADS / 64)            // 8 waves
#define XTILE   256                       // x-points per block
#define P       4                         // x-points per lane (XTILE / 64)
#define YPW     (NPTS / NWAVE)            // 512 y per wave
#define BLOCKS_PER_DIR (BATCH * (NPTS / XTILE))   // 8*16 = 128
#define TOTAL_BLOCKS   (2 * BLOCKS_PER_DIR)       // 256

// Block = one (dir, batch, x-tile of 256). Lane l owns x-points {l, l+64, l+128, l+192}.
// Wave w scans y-octant w of all 4096 y, staged once in LDS as (-2y0,-2y1,-2y2,|y|^2).
// Inner loop: 1 ds_read_b128 (wave-uniform broadcast) feeds 4 dot-chains -> 1 LDS read
// per 256 pairs; 3 fma + fused min3 per pair. |x|^2 folded in the epilogue.
__global__ __launch_bounds__(THREADS) void chamfer_min_kernel(
    const float* __restrict__ A, const float* __restrict__ Bp,
    float* __restrict__ partials)
{
    __shared__ float4 ys[NPTS];              // 64 KB transformed y
    __shared__ float  yraw[NPTS * 3];        // 48 KB raw staging (coalesced bounce)
    __shared__ float  smin[NWAVE][XTILE];    // 8 KB per-wave mins
    __shared__ float  sxs[XTILE];            // |x|^2 per x-point
    __shared__ float  rsum[XTILE];           // sum tree

    const int bid  = blockIdx.x;
    const int dir  = bid >> 7;               // 128 blocks per direction
    const int sub  = bid & 127;
    const int b    = sub >> 4;
    const int tile = sub & 15;
    const int tid  = threadIdx.x;
    const int lane = tid & 63;
    const int wave = tid >> 6;

    const float* xbase = (dir == 0 ? A : Bp) + (size_t)b * NPTS * 3;
    const float* ybase = (dir == 0 ? Bp : A) + (size_t)b * NPTS * 3;

    // ---- stage raw y coalesced (float4), then transform in LDS ----
    const float4* yg4 = (const float4*)ybase;            // 4096*3*4B, 16B-aligned
    float4* yraw4 = (float4*)yraw;
    #pragma unroll
    for (int i = tid; i < NPTS * 3 / 4; i += THREADS)
        yraw4[i] = yg4[i];
    __syncthreads();
    #pragma unroll
    for (int p = tid; p < NPTS; p += THREADS) {
        const float y0 = yraw[3 * p], y1 = yraw[3 * p + 1], y2 = yraw[3 * p + 2];
        ys[p] = make_float4(-2.f * y0, -2.f * y1, -2.f * y2,
                            y0 * y0 + y1 * y1 + y2 * y2);
    }

    // ---- x-points into registers (same 4 x for every wave) ----
    float x0[P], x1[P], x2[P], mn[P];
    #pragma unroll
    for (int p = 0; p < P; ++p) {
        const int xi = tile * XTILE + p * 64 + lane;
        x0[p] = xbase[xi * 3 + 0];
        x1[p] = xbase[xi * 3 + 1];
        x2[p] = xbase[xi * 3 + 2];
        mn[p] = FLT_MAX;
        if (wave == 0)
            sxs[p * 64 + lane] = x0[p] * x0[p] + x1[p] * x1[p] + x2[p] * x2[p];
    }
    __syncthreads();

    // ---- main loop: wave w scans its y-octant ----
    const float4* yw_ptr = &ys[wave * YPW];
    #pragma unroll 4
    for (int i = 0; i < YPW; i += 2) {
        const float4 a = yw_ptr[i];
        const float4 c = yw_ptr[i + 1];
        #pragma unroll
        for (int p = 0; p < P; ++p) {
            const float da = fmaf(x0[p], a.x, fmaf(x1[p], a.y, fmaf(x2[p], a.z, a.w)));
            const float dc = fmaf(x0[p], c.x, fmaf(x1[p], c.y, fmaf(x2[p], c.z, c.w)));
            mn[p] = fminf(mn[p], fminf(da, dc));   // fuses to v_min3_f32
        }
    }

    #pragma unroll
    for (int p = 0; p < P; ++p)
        smin[wave][p * 64 + lane] = mn[p];
    __syncthreads();

    // ---- epilogue: combine 8 octant-mins per x, clamp, deterministic sum ----
    if (tid < XTILE) {
        float m = smin[0][tid];
        #pragma unroll
        for (int w = 1; w < NWAVE; ++w) m = fminf(m, smin[w][tid]);
        rsum[tid] = fmaxf(sxs[tid] + m, 0.0f);
    }
    __syncthreads();
    #pragma unroll
    for (int s = XTILE / 2; s > 0; s >>= 1) {
        if (tid < s) rsum[tid] += rsum[tid + s];
        __syncthreads();
    }
    if (tid == 0) partials[bid] = rsum[0];
}

// Deterministic fixed-order reduction of 256 block partials.
// Both directions carry the same 1/(B*N) weight, so sum all and scale once.
__global__ __launch_bounds__(256) void chamfer_final_kernel(
    const float* __restrict__ partials, float* __restrict__ out)
{
    __shared__ float r[256];
    const int tid = threadIdx.x;
    r[tid] = partials[tid];
    __syncthreads();
    #pragma unroll
    for (int s = 128; s > 0; s >>= 1) {
        if (tid < s) r[tid] += r[tid + s];
        __syncthreads();
    }
    if (tid == 0) out[0] = r[0] * (1.0f / (BATCH * NPTS));
}

extern "C" void kernel_launch(void* const* d_in, const int* in_sizes, int n_in,
                              void* d_out, int out_size, void* d_ws, size_t ws_size,
                              hipStream_t stream) {
    const float* A = (const float*)d_in[0];   // coor_recon [8,4096,3]
    const float* B = (const float*)d_in[1];   // pc_gd      [8,4096,3]
    float* partials = (float*)d_ws;           // 256 floats, fully rewritten each call
    float* out = (float*)d_out;

    chamfer_min_kernel<<<TOTAL_BLOCKS, THREADS, 0, stream>>>(A, B, partials);
    chamfer_final_kernel<<<1, 256, 0, stream>>>(partials, out);
}